// Round 1
// 220.548 us; speedup vs baseline: 1.0711x; 1.0711x over previous
//
#include <hip/hip_runtime.h>

#define L_SEQ  2048
#define EMB    1024
#define NHEAD  16
#define HDIM   64
#define NBATCH 2

typedef unsigned short u16;
typedef unsigned int   u32;
typedef unsigned long long u64;
typedef short bf16x8 __attribute__((ext_vector_type(8)));
typedef float f32x4  __attribute__((ext_vector_type(4)));
typedef int   i32x4  __attribute__((ext_vector_type(4)));

static __device__ __forceinline__ u16 f2bf(float x) {
    union { float f; unsigned u; } a; a.f = x;
    unsigned r = a.u + 0x7FFFu + ((a.u >> 16) & 1u);
    return (u16)(r >> 16);
}
static __device__ __forceinline__ void cvt8(const float4& a, const float4& b, u16* o, float s) {
    o[0]=f2bf(a.x*s); o[1]=f2bf(a.y*s); o[2]=f2bf(a.z*s); o[3]=f2bf(a.w*s);
    o[4]=f2bf(b.x*s); o[5]=f2bf(b.y*s); o[6]=f2bf(b.z*s); o[7]=f2bf(b.w*s);
}

// packed f32x2 -> bf16x2 (RNE), dst.lo = bf16(lo), dst.hi = bf16(hi)
static __device__ __forceinline__ u32 cvt_pk_bf16(float lo, float hi) {
    u32 r;
    asm("v_cvt_pk_bf16_f32 %0, %1, %2" : "=v"(r) : "v"(lo), "v"(hi));
    return r;
}
// x=(x0,x1,x2,x3),y=(y0,y1,y2,y3) quads -> x=(x0,x1,y0,y1), y=(x2,x3,y2,y3)
static __device__ __forceinline__ void permswap32(u32 &x, u32 &y) {
    asm("v_permlane32_swap_b32 %0, %1" : "+v"(x), "+v"(y));
}
// -> x=(x0,y0,x2,y2), y=(x1,y1,x3,y3)
static __device__ __forceinline__ void permswap16(u32 &x, u32 &y) {
    asm("v_permlane16_swap_b32 %0, %1" : "+v"(x), "+v"(y));
}

// ---------------------------------------------------------------------------
// Mask bit-pack: maskp[n*2048+q][t] = 64 bits for k = t*64..t*64+63.
// ---------------------------------------------------------------------------
__global__ void pack_mask(const int* __restrict__ Mg, u64* __restrict__ maskp)
{
    const int wave = threadIdx.x >> 6;
    const int lane = threadIdx.x & 63;
    const int row  = blockIdx.x * 4 + wave;          // 0 .. 4095
    const int* mp = Mg + (size_t)row * L_SEQ + lane;
    u64* op = maskp + (size_t)row * (L_SEQ / 64);
    for (int t = 0; t < L_SEQ / 64; ++t) {
        u64 b = __ballot(mp[t * 64] != 0);
        if (lane == 0) op[t] = b;
    }
}

// ---------------------------------------------------------------------------
// QKV prep: Qb = bf16(Q * 0.125 * log2(e)) same layout [n,q,E]  (exp2 path);
// Kb = bf16(K) head-major [n,h,k,d]; Vt = bf16(V)^T head-major [n,h,d,k].
// ---------------------------------------------------------------------------
__global__ __launch_bounds__(256)
void prep_qkv(const float* __restrict__ Qg, const float* __restrict__ Kg,
              const float* __restrict__ Vg, u16* __restrict__ Qb,
              u16* __restrict__ Kb, u16* __restrict__ Vt)
{
    const int t = blockIdx.x, h = blockIdx.y, n = blockIdx.z;
    const int tid = threadIdx.x;
    const int row = tid >> 2;            // 0..63
    const int dc  = (tid & 3) * 16;      // 0,16,32,48

    __shared__ u16 Vl2[64][72];          // [d][k_row]

    const size_t gin = ((size_t)(n * L_SEQ) + t * 64 + row) * EMB + h * HDIM + dc;

    // Q: scale (1/8 * log2e) + convert, same layout
    {
        const float qs = 0.125f * 1.44269504f;
        u16 o[16];
        cvt8(*(const float4*)(Qg + gin),     *(const float4*)(Qg + gin + 4),  o,     qs);
        cvt8(*(const float4*)(Qg + gin + 8), *(const float4*)(Qg + gin + 12), o + 8, qs);
        *(uint4*)(Qb + gin)     = *(const uint4*)o;
        *(uint4*)(Qb + gin + 8) = *(const uint4*)&o[8];
    }
    // K: convert, head-major
    {
        u16 o[16];
        cvt8(*(const float4*)(Kg + gin),     *(const float4*)(Kg + gin + 4),  o,     1.f);
        cvt8(*(const float4*)(Kg + gin + 8), *(const float4*)(Kg + gin + 12), o + 8, 1.f);
        size_t ko = ((size_t)(n * NHEAD + h) * L_SEQ + t * 64 + row) * HDIM + dc;
        *(uint4*)(Kb + ko)     = *(const uint4*)o;
        *(uint4*)(Kb + ko + 8) = *(const uint4*)&o[8];
    }
    // V: convert + transpose via LDS
    {
        u16 o[16];
        cvt8(*(const float4*)(Vg + gin),     *(const float4*)(Vg + gin + 4),  o,     1.f);
        cvt8(*(const float4*)(Vg + gin + 8), *(const float4*)(Vg + gin + 12), o + 8, 1.f);
        #pragma unroll
        for (int j = 0; j < 16; ++j) Vl2[dc + j][row] = o[j];
    }
    __syncthreads();
    {
        const int d  = tid >> 2;
        const int kc = (tid & 3) * 16;
        size_t vo = ((size_t)(n * NHEAD + h) * HDIM + d) * L_SEQ + t * 64 + kc;
        *(uint4*)(Vt + vo)     = *(const uint4*)&Vl2[d][kc];
        *(uint4*)(Vt + vo + 8) = *(const uint4*)&Vl2[d][kc + 8];
    }
}

// ---------------------------------------------------------------------------
// W fp32 -> bf16
// ---------------------------------------------------------------------------
__global__ void wcvt(const float* __restrict__ W, u16* __restrict__ Wb)
{
    int i = (blockIdx.x * 256 + threadIdx.x) * 8;
    float4 a = *(const float4*)(W + i);
    float4 b = *(const float4*)(W + i + 4);
    u16 o[8];
    cvt8(a, b, o, 1.f);
    *(uint4*)(Wb + i) = *(const uint4*)o;
}

// ---------------------------------------------------------------------------
// Flash attention, zero-bias exp2 softmax (p = 2^s2, s2 = (q.k)/8*log2e;
// the bias cancels in the final normalize; |s2| <~ 10 so no overflow).
// Swapped QK^T (S^T = mfma(K,Q)) makes each lane own one q-row; P goes
// C-layout -> B-fragment entirely in registers: 8 cvt_pk_bf16 + 8 permlane
// swaps per 64-k tile. No P LDS buffer, no scalar ds writes.
// ---------------------------------------------------------------------------
__global__ __launch_bounds__(256, 4)
void attn_kernel(const u16* __restrict__ Qb, const u16* __restrict__ Kb,
                 const u16* __restrict__ Vt, const u64* __restrict__ maskp,
                 u16* __restrict__ Og)
{
    const int qblk = blockIdx.x;
    const int h    = blockIdx.y;
    const int n    = blockIdx.z;
    const int tid  = threadIdx.x;
    const int wave = tid >> 6;
    const int lane = tid & 63;
    const int l16  = lane & 15;
    const int quad = lane >> 4;

    __shared__ u16 Kl[64][72];      // [k][d]
    __shared__ u16 Vl[64][72];      // [d][k]

    const int q0 = qblk * 64 + wave * 16;

    // Q fragment (pre-scaled bf16). Used as the B-operand of swapped QK^T:
    // B[row=q=l16][kdim = quad*8+j] -- same fragment bytes as before.
    bf16x8 qf[2];
    {
        const u16* qp = Qb + ((size_t)(n * L_SEQ) + q0 + l16) * EMB + h * HDIM;
        qf[0] = *(const bf16x8*)(qp + quad * 8);
        qf[1] = *(const bf16x8*)(qp + 32 + quad * 8);
    }

    f32x4 acc[4];
    #pragma unroll
    for (int c = 0; c < 4; ++c)
        #pragma unroll
        for (int r = 0; r < 4; ++r) acc[c][r] = 0.f;
    float lsum = 0.f;      // per-lane partial row-sum, q = l16, k in this lane's 16 slots

    const u16* kbase = Kb + (size_t)(n * NHEAD + h) * L_SEQ * HDIM;
    const u16* vbase = Vt + (size_t)(n * NHEAD + h) * HDIM * L_SEQ;
    const u64* mbase = maskp + ((size_t)(n * L_SEQ) + q0 + l16) * (L_SEQ / 64);

    const int srow = tid >> 2;           // 0..63
    const int scol = (tid & 3) * 16;     // 0,16,32,48

    uint4 kr0, kr1, vr0, vr1;
    u64 mr;

    // prologue: prefetch tile 0
    {
        const u16* kp = kbase + (size_t)srow * HDIM + scol;
        const u16* vp = vbase + (size_t)srow * L_SEQ + scol;
        kr0 = *(const uint4*)kp;  kr1 = *(const uint4*)(kp + 8);
        vr0 = *(const uint4*)vp;  vr1 = *(const uint4*)(vp + 8);
        mr  = mbase[0];
    }

    for (int t = 0; t < L_SEQ / 64; ++t) {
        __syncthreads();
        *(uint4*)&Kl[srow][scol]     = kr0;
        *(uint4*)&Kl[srow][scol + 8] = kr1;
        *(uint4*)&Vl[srow][scol]     = vr0;
        *(uint4*)&Vl[srow][scol + 8] = vr1;
        u64 mcur = mr;

        if (t + 1 < L_SEQ / 64) {
            const u16* kp = kbase + (size_t)((t + 1) * 64 + srow) * HDIM + scol;
            const u16* vp = vbase + (size_t)srow * L_SEQ + (t + 1) * 64 + scol;
            kr0 = *(const uint4*)kp;  kr1 = *(const uint4*)(kp + 8);
            vr0 = *(const uint4*)vp;  vr1 = *(const uint4*)(vp + 8);
            mr  = mbase[t + 1];
        }
        __syncthreads();

        // ---- S^T = K (Q)^T, swapped: St[cc][r] = s2[q=l16][k=cc*16+quad*4+r] ----
        f32x4 St[4];
        #pragma unroll
        for (int cc = 0; cc < 4; ++cc) {
            bf16x8 k0 = *(const bf16x8*)&Kl[cc * 16 + l16][quad * 8];
            bf16x8 k1 = *(const bf16x8*)&Kl[cc * 16 + l16][32 + quad * 8];
            f32x4 z; z[0]=0.f; z[1]=0.f; z[2]=0.f; z[3]=0.f;
            z = __builtin_amdgcn_mfma_f32_16x16x32_bf16(k0, qf[0], z, 0, 0, 0);
            z = __builtin_amdgcn_mfma_f32_16x16x32_bf16(k1, qf[1], z, 0, 0, 0);
            St[cc] = z;
        }

        // ---- p = mask ? 2^s2 : 0 ; pack to bf16 dwords (k-pairs) ----
        // lane's mask bits: k = cc*16 + quad*4 + r  ->  bit (cc&1)*16 + r of lo/hi
        u32 lo  = (u32)(mcur >> (quad * 4));
        u32 hiw = (u32)(mcur >> (quad * 4 + 32));
        u32 Dw[8];   // Dw[2*cc+hh] = bf16x2 of P[q=l16][k=cc*16+quad*4+2hh (+1)]
        #pragma unroll
        for (int cc = 0; cc < 4; ++cc) {
            u32 w = (cc < 2) ? lo : hiw;
            float pv[4];
            #pragma unroll
            for (int r = 0; r < 4; ++r) {
                const int pos = (cc & 1) * 16 + r;
                int sm = (int)(w << (31 - pos)) >> 31;        // 0 or -1 (bfe_i32)
                float p = __builtin_amdgcn_exp2f(St[cc][r]);
                p = __int_as_float(__float_as_int(p) & sm);
                lsum += p;
                pv[r] = p;
            }
            Dw[2 * cc]     = cvt_pk_bf16(pv[0], pv[1]);
            Dw[2 * cc + 1] = cvt_pk_bf16(pv[2], pv[3]);
        }

        // ---- O^T += V^T P^T : in-register quad redistribution -> B-fragment ----
        // target (quad p, kc): Bj dwords are k-pairs kc*32+8p+2j; composition
        // permswap32 then permswap16 on (Dw[4kc], Dw[4kc+2]) yields (B0,B2),
        // on (Dw[4kc+1], Dw[4kc+3]) yields (B1,B3).
        #pragma unroll
        for (int kc = 0; kc < 2; ++kc) {
            u32 b0 = Dw[4 * kc + 0], b2 = Dw[4 * kc + 2];
            permswap32(b0, b2); permswap16(b0, b2);
            u32 b1 = Dw[4 * kc + 1], b3 = Dw[4 * kc + 3];
            permswap32(b1, b3); permswap16(b1, b3);
            union { i32x4 i; bf16x8 v; } pu;
            pu.i[0] = (int)b0; pu.i[1] = (int)b1; pu.i[2] = (int)b2; pu.i[3] = (int)b3;
            bf16x8 pf = pu.v;
            #pragma unroll
            for (int dc = 0; dc < 4; ++dc) {
                bf16x8 vf = *(const bf16x8*)&Vl[dc * 16 + l16][kc * 32 + quad * 8];
                acc[dc] = __builtin_amdgcn_mfma_f32_16x16x32_bf16(vf, pf, acc[dc], 0, 0, 0);
            }
        }
    }

    // ---- final: sum over the 4 quads (same l16 = same q), normalize, write ----
    // acc[dc][r] = O[q = l16][d = dc*16 + quad*4 + r] (unnormalized)
    float s = lsum;
    s += __shfl_xor(s, 16);
    s += __shfl_xor(s, 32);
    float inv = 1.f / s;

    u16* op = Og + ((size_t)(n * L_SEQ) + q0 + l16) * EMB + h * HDIM + quad * 4;
    #pragma unroll
    for (int dc = 0; dc < 4; ++dc) {
        u32 u0 = cvt_pk_bf16(acc[dc][0] * inv, acc[dc][1] * inv);
        u32 u1 = cvt_pk_bf16(acc[dc][2] * inv, acc[dc][3] * inv);
        uint2 st; st.x = u0; st.y = u1;
        *(uint2*)(op + dc * 16) = st;
    }
}

// ---------------------------------------------------------------------------
// out(fp32) = attn(4096x1024 bf16) @ Wb^T + bias.
// ---------------------------------------------------------------------------
__global__ __launch_bounds__(256, 4)
void out_gemm(const u16* __restrict__ A, const u16* __restrict__ B,
              const float* __restrict__ bias, float* __restrict__ out)
{
    const int bn  = blockIdx.x;   // 0..15
    const int bm  = blockIdx.y;   // 0..63
    const int tid = threadIdx.x;
    const int wave = tid >> 6;
    const int lane = tid & 63;
    const int l16  = lane & 15;
    const int quad = lane >> 4;
    const int wr = wave >> 1, wc = wave & 1;

    __shared__ u16 Al[64][72];
    __shared__ u16 Bl[64][72];

    f32x4 acc[2][2];
    #pragma unroll
    for (int i = 0; i < 2; ++i)
        #pragma unroll
        for (int j = 0; j < 2; ++j)
            #pragma unroll
            for (int r = 0; r < 4; ++r) acc[i][j][r] = 0.f;

    const int srow = tid >> 2;          // 0..63
    const int kc   = (tid & 3) * 16;    // 0,16,32,48

    const u16* ap = A + (size_t)(bm * 64 + srow) * EMB + kc;
    const u16* bp = B + (size_t)(bn * 64 + srow) * EMB + kc;

    uint4 ar0 = *(const uint4*)ap,        ar1 = *(const uint4*)(ap + 8);
    uint4 br0 = *(const uint4*)bp,        br1 = *(const uint4*)(bp + 8);

    for (int k0 = 0; k0 < EMB; k0 += 64) {
        __syncthreads();
        *(uint4*)&Al[srow][kc]     = ar0;
        *(uint4*)&Al[srow][kc + 8] = ar1;
        *(uint4*)&Bl[srow][kc]     = br0;
        *(uint4*)&Bl[srow][kc + 8] = br1;
        if (k0 + 64 < EMB) {
            ar0 = *(const uint4*)(ap + k0 + 64);  ar1 = *(const uint4*)(ap + k0 + 72);
            br0 = *(const uint4*)(bp + k0 + 64);  br1 = *(const uint4*)(bp + k0 + 72);
        }
        __syncthreads();

        #pragma unroll
        for (int kk = 0; kk < 2; ++kk) {
            bf16x8 af[2], bfr[2];
            #pragma unroll
            for (int i = 0; i < 2; ++i)
                af[i] = *(const bf16x8*)&Al[wr * 32 + i * 16 + l16][kk * 32 + quad * 8];
            #pragma unroll
            for (int j = 0; j < 2; ++j)
                bfr[j] = *(const bf16x8*)&Bl[wc * 32 + j * 16 + l16][kk * 32 + quad * 8];
            #pragma unroll
            for (int i = 0; i < 2; ++i)
                #pragma unroll
                for (int j = 0; j < 2; ++j)
                    acc[i][j] = __builtin_amdgcn_mfma_f32_16x16x32_bf16(af[i], bfr[j], acc[i][j], 0, 0, 0);
        }
    }

    #pragma unroll
    for (int j = 0; j < 2; ++j) {
        int col = bn * 64 + wc * 32 + j * 16 + l16;
        float bv = bias[col];
        #pragma unroll
        for (int i = 0; i < 2; ++i) {
            int row0 = bm * 64 + wr * 32 + i * 16 + quad * 4;
            #pragma unroll
            for (int r = 0; r < 4; ++r)
                out[(size_t)(row0 + r) * EMB + col] = acc[i][j][r] + bv;
        }
    }
}

extern "C" void kernel_launch(void* const* d_in, const int* in_sizes, int n_in,
                              void* d_out, int out_size, void* d_ws, size_t ws_size,
                              hipStream_t stream)
{
    const float* Vg = (const float*)d_in[0];
    const float* Kg = (const float*)d_in[1];
    const float* Qg = (const float*)d_in[2];
    const int*   Mg = (const int*)d_in[3];
    const float* Wg = (const float*)d_in[4];
    const float* Bg = (const float*)d_in[5];
    float* Og = (float*)d_out;

    const size_t QKV = (size_t)NBATCH * L_SEQ * EMB;   // 4M elems
    char* ws = (char*)d_ws;
    u16* attn_ws = (u16*)ws;                         // 8 MB
    u16* Wb      = (u16*)(ws + QKV * 2);             // 2 MB
    u16* Qb      = (u16*)(ws + QKV * 2 + 2 * 1024 * 1024);
    u16* Kb      = Qb + QKV;                         // 8 MB each
    u16* Vt      = Kb + QKV;
    u64* maskp   = (u64*)(Vt + QKV);                 // 1 MB

    pack_mask<<<dim3(NBATCH * L_SEQ / 4), 256, 0, stream>>>(Mg, maskp);
    prep_qkv<<<dim3(L_SEQ / 64, NHEAD, NBATCH), 256, 0, stream>>>(Qg, Kg, Vg, Qb, Kb, Vt);
    wcvt<<<dim3(EMB * EMB / (256 * 8)), 256, 0, stream>>>(Wg, Wb);

    dim3 g1(L_SEQ / 64, NHEAD, NBATCH);
    attn_kernel<<<g1, 256, 0, stream>>>(Qb, Kb, Vt, maskp, attn_ws);

    dim3 g2(EMB / 64, (NBATCH * L_SEQ) / 64);
    out_gemm<<<g2, 256, 0, stream>>>(attn_ws, Wb, Bg, Og);
}

// Round 2
// 220.448 us; speedup vs baseline: 1.0716x; 1.0005x over previous
//
#include <hip/hip_runtime.h>

#define L_SEQ  2048
#define EMB    1024
#define NHEAD  16
#define HDIM   64
#define NBATCH 2

typedef unsigned short u16;
typedef unsigned int   u32;
typedef unsigned long long u64;
typedef short bf16x8 __attribute__((ext_vector_type(8)));
typedef float f32x4  __attribute__((ext_vector_type(4)));
typedef int   i32x4  __attribute__((ext_vector_type(4)));

static __device__ __forceinline__ u16 f2bf(float x) {
    union { float f; unsigned u; } a; a.f = x;
    unsigned r = a.u + 0x7FFFu + ((a.u >> 16) & 1u);
    return (u16)(r >> 16);
}
static __device__ __forceinline__ void cvt8(const float4& a, const float4& b, u16* o, float s) {
    o[0]=f2bf(a.x*s); o[1]=f2bf(a.y*s); o[2]=f2bf(a.z*s); o[3]=f2bf(a.w*s);
    o[4]=f2bf(b.x*s); o[5]=f2bf(b.y*s); o[6]=f2bf(b.z*s); o[7]=f2bf(b.w*s);
}

// packed f32x2 -> bf16x2 (RNE), dst.lo = bf16(lo), dst.hi = bf16(hi)
static __device__ __forceinline__ u32 cvt_pk_bf16(float lo, float hi) {
    u32 r;
    asm("v_cvt_pk_bf16_f32 %0, %1, %2" : "=v"(r) : "v"(lo), "v"(hi));
    return r;
}
// x=(x0,x1,x2,x3),y=(y0,y1,y2,y3) quads -> x=(x0,x1,y0,y1), y=(x2,x3,y2,y3)
static __device__ __forceinline__ void permswap32(u32 &x, u32 &y) {
    asm("v_permlane32_swap_b32 %0, %1" : "+v"(x), "+v"(y));
}
// -> x=(x0,y0,x2,y2), y=(x1,y1,x3,y3)
static __device__ __forceinline__ void permswap16(u32 &x, u32 &y) {
    asm("v_permlane16_swap_b32 %0, %1" : "+v"(x), "+v"(y));
}

// ---------------------------------------------------------------------------
// Mask bit-pack: maskp[n*2048+q][t] = 64 bits for k = t*64..t*64+63.
// ---------------------------------------------------------------------------
__global__ void pack_mask(const int* __restrict__ Mg, u64* __restrict__ maskp)
{
    const int wave = threadIdx.x >> 6;
    const int lane = threadIdx.x & 63;
    const int row  = blockIdx.x * 4 + wave;          // 0 .. 4095
    const int* mp = Mg + (size_t)row * L_SEQ + lane;
    u64* op = maskp + (size_t)row * (L_SEQ / 64);
    for (int t = 0; t < L_SEQ / 64; ++t) {
        u64 b = __ballot(mp[t * 64] != 0);
        if (lane == 0) op[t] = b;
    }
}

// ---------------------------------------------------------------------------
// QKV prep: Qb = bf16(Q * 0.125 * log2(e)) same layout [n,q,E]  (exp2 path);
// Kb = bf16(K) head-major [n,h,k,d]; Vt = bf16(V)^T head-major [n,h,d,k].
// ---------------------------------------------------------------------------
__global__ __launch_bounds__(256)
void prep_qkv(const float* __restrict__ Qg, const float* __restrict__ Kg,
              const float* __restrict__ Vg, u16* __restrict__ Qb,
              u16* __restrict__ Kb, u16* __restrict__ Vt)
{
    const int t = blockIdx.x, h = blockIdx.y, n = blockIdx.z;
    const int tid = threadIdx.x;
    const int row = tid >> 2;            // 0..63
    const int dc  = (tid & 3) * 16;      // 0,16,32,48

    __shared__ u16 Vl2[64][72];          // [d][k_row]

    const size_t gin = ((size_t)(n * L_SEQ) + t * 64 + row) * EMB + h * HDIM + dc;

    // Q: scale (1/8 * log2e) + convert, same layout
    {
        const float qs = 0.125f * 1.44269504f;
        u16 o[16];
        cvt8(*(const float4*)(Qg + gin),     *(const float4*)(Qg + gin + 4),  o,     qs);
        cvt8(*(const float4*)(Qg + gin + 8), *(const float4*)(Qg + gin + 12), o + 8, qs);
        *(uint4*)(Qb + gin)     = *(const uint4*)o;
        *(uint4*)(Qb + gin + 8) = *(const uint4*)&o[8];
    }
    // K: convert, head-major
    {
        u16 o[16];
        cvt8(*(const float4*)(Kg + gin),     *(const float4*)(Kg + gin + 4),  o,     1.f);
        cvt8(*(const float4*)(Kg + gin + 8), *(const float4*)(Kg + gin + 12), o + 8, 1.f);
        size_t ko = ((size_t)(n * NHEAD + h) * L_SEQ + t * 64 + row) * HDIM + dc;
        *(uint4*)(Kb + ko)     = *(const uint4*)o;
        *(uint4*)(Kb + ko + 8) = *(const uint4*)&o[8];
    }
    // V: convert + transpose via LDS
    {
        u16 o[16];
        cvt8(*(const float4*)(Vg + gin),     *(const float4*)(Vg + gin + 4),  o,     1.f);
        cvt8(*(const float4*)(Vg + gin + 8), *(const float4*)(Vg + gin + 12), o + 8, 1.f);
        #pragma unroll
        for (int j = 0; j < 16; ++j) Vl2[dc + j][row] = o[j];
    }
    __syncthreads();
    {
        const int d  = tid >> 2;
        const int kc = (tid & 3) * 16;
        size_t vo = ((size_t)(n * NHEAD + h) * HDIM + d) * L_SEQ + t * 64 + kc;
        *(uint4*)(Vt + vo)     = *(const uint4*)&Vl2[d][kc];
        *(uint4*)(Vt + vo + 8) = *(const uint4*)&Vl2[d][kc + 8];
    }
}

// ---------------------------------------------------------------------------
// W fp32 -> bf16
// ---------------------------------------------------------------------------
__global__ void wcvt(const float* __restrict__ W, u16* __restrict__ Wb)
{
    int i = (blockIdx.x * 256 + threadIdx.x) * 8;
    float4 a = *(const float4*)(W + i);
    float4 b = *(const float4*)(W + i + 4);
    u16 o[8];
    cvt8(a, b, o, 1.f);
    *(uint4*)(Wb + i) = *(const uint4*)o;
}

// ---------------------------------------------------------------------------
// Flash attention, zero-bias exp2 softmax. Swapped QK^T; P goes C-layout ->
// B-fragment in registers (cvt_pk + permlane swaps). 128 q-rows per block,
// 32 q-rows per wave (two 16-row sets): K/V LDS fragment reads are loaded
// once per tile and reused for both q-sets, halving LDS traffic per q-row.
// ---------------------------------------------------------------------------
__global__ __launch_bounds__(256, 2)
void attn_kernel(const u16* __restrict__ Qb, const u16* __restrict__ Kb,
                 const u16* __restrict__ Vt, const u64* __restrict__ maskp,
                 u16* __restrict__ Og)
{
    const int qblk = blockIdx.x;    // 0..15 (128 q-rows each)
    const int h    = blockIdx.y;
    const int n    = blockIdx.z;
    const int tid  = threadIdx.x;
    const int wave = tid >> 6;
    const int lane = tid & 63;
    const int l16  = lane & 15;
    const int quad = lane >> 4;

    __shared__ u16 Kl[64][72];      // [k][d]
    __shared__ u16 Vl[64][72];      // [d][k]

    const int q0 = qblk * 128 + wave * 32;

    // Q fragments (pre-scaled bf16), B-operand of swapped QK^T; two q-sets.
    bf16x8 qf[2][2];
    #pragma unroll
    for (int qs = 0; qs < 2; ++qs) {
        const u16* qp = Qb + ((size_t)(n * L_SEQ) + q0 + qs * 16 + l16) * EMB + h * HDIM;
        qf[qs][0] = *(const bf16x8*)(qp + quad * 8);
        qf[qs][1] = *(const bf16x8*)(qp + 32 + quad * 8);
    }

    f32x4 acc[2][4];
    #pragma unroll
    for (int qs = 0; qs < 2; ++qs)
        #pragma unroll
        for (int c = 0; c < 4; ++c)
            #pragma unroll
            for (int r = 0; r < 4; ++r) acc[qs][c][r] = 0.f;
    float lsum[2] = {0.f, 0.f};

    const u16* kbase = Kb + (size_t)(n * NHEAD + h) * L_SEQ * HDIM;
    const u16* vbase = Vt + (size_t)(n * NHEAD + h) * HDIM * L_SEQ;
    const u64* mbase = maskp + ((size_t)(n * L_SEQ) + q0 + l16) * (L_SEQ / 64);
    const int  mqs   = 16 * (L_SEQ / 64);    // row stride for second q-set

    const int srow = tid >> 2;           // 0..63
    const int scol = (tid & 3) * 16;     // 0,16,32,48

    uint4 kr0, kr1, vr0, vr1;
    u64 mr[2];

    // prologue: prefetch tile 0
    {
        const u16* kp = kbase + (size_t)srow * HDIM + scol;
        const u16* vp = vbase + (size_t)srow * L_SEQ + scol;
        kr0 = *(const uint4*)kp;  kr1 = *(const uint4*)(kp + 8);
        vr0 = *(const uint4*)vp;  vr1 = *(const uint4*)(vp + 8);
        mr[0] = mbase[0];
        mr[1] = mbase[mqs];
    }

    for (int t = 0; t < L_SEQ / 64; ++t) {
        __syncthreads();
        *(uint4*)&Kl[srow][scol]     = kr0;
        *(uint4*)&Kl[srow][scol + 8] = kr1;
        *(uint4*)&Vl[srow][scol]     = vr0;
        *(uint4*)&Vl[srow][scol + 8] = vr1;
        u64 mcur0 = mr[0], mcur1 = mr[1];

        if (t + 1 < L_SEQ / 64) {
            const u16* kp = kbase + (size_t)((t + 1) * 64 + srow) * HDIM + scol;
            const u16* vp = vbase + (size_t)srow * L_SEQ + (t + 1) * 64 + scol;
            kr0 = *(const uint4*)kp;  kr1 = *(const uint4*)(kp + 8);
            vr0 = *(const uint4*)vp;  vr1 = *(const uint4*)(vp + 8);
            mr[0] = mbase[t + 1];
            mr[1] = mbase[mqs + t + 1];
        }
        __syncthreads();

        // mask words, u32-half shifts (bits needed are all within each half)
        const int sh = quad * 4;
        u32 mlo[2], mhi[2];
        mlo[0] = (u32)mcur0 >> sh;  mhi[0] = (u32)(mcur0 >> 32) >> sh;
        mlo[1] = (u32)mcur1 >> sh;  mhi[1] = (u32)(mcur1 >> 32) >> sh;

        // ---- per k-column-block: S^T = K Q^T for both q-sets, then softmax ----
        u32 Dw[2][8];   // Dw[qs][2*cc+hh] = bf16x2 of P[q][k=cc*16+quad*4+2hh(+1)]
        #pragma unroll
        for (int cc = 0; cc < 4; ++cc) {
            bf16x8 k0 = *(const bf16x8*)&Kl[cc * 16 + l16][quad * 8];
            bf16x8 k1 = *(const bf16x8*)&Kl[cc * 16 + l16][32 + quad * 8];
            f32x4 z0; z0[0]=0.f; z0[1]=0.f; z0[2]=0.f; z0[3]=0.f;
            f32x4 z1 = z0;
            z0 = __builtin_amdgcn_mfma_f32_16x16x32_bf16(k0, qf[0][0], z0, 0, 0, 0);
            z0 = __builtin_amdgcn_mfma_f32_16x16x32_bf16(k1, qf[0][1], z0, 0, 0, 0);
            z1 = __builtin_amdgcn_mfma_f32_16x16x32_bf16(k0, qf[1][0], z1, 0, 0, 0);
            z1 = __builtin_amdgcn_mfma_f32_16x16x32_bf16(k1, qf[1][1], z1, 0, 0, 0);

            #pragma unroll
            for (int qs = 0; qs < 2; ++qs) {
                const f32x4& z = (qs == 0) ? z0 : z1;
                u32 w = (cc < 2) ? mlo[qs] : mhi[qs];
                float pv[4];
                #pragma unroll
                for (int r = 0; r < 4; ++r) {
                    const int pos = (cc & 1) * 16 + r;
                    int sm = (int)(w << (31 - pos)) >> 31;        // 0 or -1 (bfe_i32)
                    float p = __builtin_amdgcn_exp2f(z[r]);
                    p = __int_as_float(__float_as_int(p) & sm);
                    lsum[qs] += p;
                    pv[r] = p;
                }
                Dw[qs][2 * cc]     = cvt_pk_bf16(pv[0], pv[1]);
                Dw[qs][2 * cc + 1] = cvt_pk_bf16(pv[2], pv[3]);
            }
        }

        // ---- O^T += V^T P^T : in-register quad redistribution -> B-fragment;
        //      V fragments loaded once, used by both q-sets ----
        #pragma unroll
        for (int kc = 0; kc < 2; ++kc) {
            bf16x8 pf[2];
            #pragma unroll
            for (int qs = 0; qs < 2; ++qs) {
                u32 b0 = Dw[qs][4 * kc + 0], b2 = Dw[qs][4 * kc + 2];
                permswap32(b0, b2); permswap16(b0, b2);
                u32 b1 = Dw[qs][4 * kc + 1], b3 = Dw[qs][4 * kc + 3];
                permswap32(b1, b3); permswap16(b1, b3);
                union { i32x4 i; bf16x8 v; } pu;
                pu.i[0] = (int)b0; pu.i[1] = (int)b1; pu.i[2] = (int)b2; pu.i[3] = (int)b3;
                pf[qs] = pu.v;
            }
            #pragma unroll
            for (int dc = 0; dc < 4; ++dc) {
                bf16x8 vf = *(const bf16x8*)&Vl[dc * 16 + l16][kc * 32 + quad * 8];
                acc[0][dc] = __builtin_amdgcn_mfma_f32_16x16x32_bf16(vf, pf[0], acc[0][dc], 0, 0, 0);
                acc[1][dc] = __builtin_amdgcn_mfma_f32_16x16x32_bf16(vf, pf[1], acc[1][dc], 0, 0, 0);
            }
        }
    }

    // ---- final: sum over the 4 quads (same l16 = same q), normalize, write ----
    #pragma unroll
    for (int qs = 0; qs < 2; ++qs) {
        float s = lsum[qs];
        s += __shfl_xor(s, 16);
        s += __shfl_xor(s, 32);
        float inv = 1.f / s;

        u16* op = Og + ((size_t)(n * L_SEQ) + q0 + qs * 16 + l16) * EMB + h * HDIM + quad * 4;
        #pragma unroll
        for (int dc = 0; dc < 4; ++dc) {
            u32 u0 = cvt_pk_bf16(acc[qs][dc][0] * inv, acc[qs][dc][1] * inv);
            u32 u1 = cvt_pk_bf16(acc[qs][dc][2] * inv, acc[qs][dc][3] * inv);
            uint2 st; st.x = u0; st.y = u1;
            *(uint2*)(op + dc * 16) = st;
        }
    }
}

// ---------------------------------------------------------------------------
// out(fp32) = attn(4096x1024 bf16) @ Wb^T + bias.
// ---------------------------------------------------------------------------
__global__ __launch_bounds__(256, 4)
void out_gemm(const u16* __restrict__ A, const u16* __restrict__ B,
              const float* __restrict__ bias, float* __restrict__ out)
{
    const int bn  = blockIdx.x;   // 0..15
    const int bm  = blockIdx.y;   // 0..63
    const int tid = threadIdx.x;
    const int wave = tid >> 6;
    const int lane = tid & 63;
    const int l16  = lane & 15;
    const int quad = lane >> 4;
    const int wr = wave >> 1, wc = wave & 1;

    __shared__ u16 Al[64][72];
    __shared__ u16 Bl[64][72];

    f32x4 acc[2][2];
    #pragma unroll
    for (int i = 0; i < 2; ++i)
        #pragma unroll
        for (int j = 0; j < 2; ++j)
            #pragma unroll
            for (int r = 0; r < 4; ++r) acc[i][j][r] = 0.f;

    const int srow = tid >> 2;          // 0..63
    const int kc   = (tid & 3) * 16;    // 0,16,32,48

    const u16* ap = A + (size_t)(bm * 64 + srow) * EMB + kc;
    const u16* bp = B + (size_t)(bn * 64 + srow) * EMB + kc;

    uint4 ar0 = *(const uint4*)ap,        ar1 = *(const uint4*)(ap + 8);
    uint4 br0 = *(const uint4*)bp,        br1 = *(const uint4*)(bp + 8);

    for (int k0 = 0; k0 < EMB; k0 += 64) {
        __syncthreads();
        *(uint4*)&Al[srow][kc]     = ar0;
        *(uint4*)&Al[srow][kc + 8] = ar1;
        *(uint4*)&Bl[srow][kc]     = br0;
        *(uint4*)&Bl[srow][kc + 8] = br1;
        if (k0 + 64 < EMB) {
            ar0 = *(const uint4*)(ap + k0 + 64);  ar1 = *(const uint4*)(ap + k0 + 72);
            br0 = *(const uint4*)(bp + k0 + 64);  br1 = *(const uint4*)(bp + k0 + 72);
        }
        __syncthreads();

        #pragma unroll
        for (int kk = 0; kk < 2; ++kk) {
            bf16x8 af[2], bfr[2];
            #pragma unroll
            for (int i = 0; i < 2; ++i)
                af[i] = *(const bf16x8*)&Al[wr * 32 + i * 16 + l16][kk * 32 + quad * 8];
            #pragma unroll
            for (int j = 0; j < 2; ++j)
                bfr[j] = *(const bf16x8*)&Bl[wc * 32 + j * 16 + l16][kk * 32 + quad * 8];
            #pragma unroll
            for (int i = 0; i < 2; ++i)
                #pragma unroll
                for (int j = 0; j < 2; ++j)
                    acc[i][j] = __builtin_amdgcn_mfma_f32_16x16x32_bf16(af[i], bfr[j], acc[i][j], 0, 0, 0);
        }
    }

    #pragma unroll
    for (int j = 0; j < 2; ++j) {
        int col = bn * 64 + wc * 32 + j * 16 + l16;
        float bv = bias[col];
        #pragma unroll
        for (int i = 0; i < 2; ++i) {
            int row0 = bm * 64 + wr * 32 + i * 16 + quad * 4;
            #pragma unroll
            for (int r = 0; r < 4; ++r)
                out[(size_t)(row0 + r) * EMB + col] = acc[i][j][r] + bv;
        }
    }
}

extern "C" void kernel_launch(void* const* d_in, const int* in_sizes, int n_in,
                              void* d_out, int out_size, void* d_ws, size_t ws_size,
                              hipStream_t stream)
{
    const float* Vg = (const float*)d_in[0];
    const float* Kg = (const float*)d_in[1];
    const float* Qg = (const float*)d_in[2];
    const int*   Mg = (const int*)d_in[3];
    const float* Wg = (const float*)d_in[4];
    const float* Bg = (const float*)d_in[5];
    float* Og = (float*)d_out;

    const size_t QKV = (size_t)NBATCH * L_SEQ * EMB;   // 4M elems
    char* ws = (char*)d_ws;
    u16* attn_ws = (u16*)ws;                         // 8 MB
    u16* Wb      = (u16*)(ws + QKV * 2);             // 2 MB
    u16* Qb      = (u16*)(ws + QKV * 2 + 2 * 1024 * 1024);
    u16* Kb      = Qb + QKV;                         // 8 MB each
    u16* Vt      = Kb + QKV;
    u64* maskp   = (u64*)(Vt + QKV);                 // 1 MB

    pack_mask<<<dim3(NBATCH * L_SEQ / 4), 256, 0, stream>>>(Mg, maskp);
    prep_qkv<<<dim3(L_SEQ / 64, NHEAD, NBATCH), 256, 0, stream>>>(Qg, Kg, Vg, Qb, Kb, Vt);
    wcvt<<<dim3(EMB * EMB / (256 * 8)), 256, 0, stream>>>(Wg, Wb);

    dim3 g1(L_SEQ / 128, NHEAD, NBATCH);
    attn_kernel<<<g1, 256, 0, stream>>>(Qb, Kb, Vt, maskp, attn_ws);

    dim3 g2(EMB / 64, (NBATCH * L_SEQ) / 64);
    out_gemm<<<g2, 256, 0, stream>>>(attn_ws, Wb, Bg, Og);
}

// Round 3
// 204.401 us; speedup vs baseline: 1.1557x; 1.0785x over previous
//
#include <hip/hip_runtime.h>

#define L_SEQ  2048
#define EMB    1024
#define NHEAD  16
#define HDIM   64
#define NBATCH 2
#define NT     (L_SEQ / 64)   // 32 k-tiles

typedef unsigned short u16;
typedef unsigned int   u32;
typedef unsigned long long u64;
typedef short bf16x8 __attribute__((ext_vector_type(8)));
typedef float f32x4  __attribute__((ext_vector_type(4)));
typedef int   i32x4  __attribute__((ext_vector_type(4)));

static __device__ __forceinline__ u16 f2bf(float x) {
    union { float f; unsigned u; } a; a.f = x;
    unsigned r = a.u + 0x7FFFu + ((a.u >> 16) & 1u);
    return (u16)(r >> 16);
}
static __device__ __forceinline__ void cvt8(const float4& a, const float4& b, u16* o, float s) {
    o[0]=f2bf(a.x*s); o[1]=f2bf(a.y*s); o[2]=f2bf(a.z*s); o[3]=f2bf(a.w*s);
    o[4]=f2bf(b.x*s); o[5]=f2bf(b.y*s); o[6]=f2bf(b.z*s); o[7]=f2bf(b.w*s);
}

// packed f32x2 -> bf16x2 (RNE), dst.lo = bf16(lo), dst.hi = bf16(hi)
static __device__ __forceinline__ u32 cvt_pk_bf16(float lo, float hi) {
    u32 r;
    asm("v_cvt_pk_bf16_f32 %0, %1, %2" : "=v"(r) : "v"(lo), "v"(hi));
    return r;
}
// x=(x0,x1,x2,x3),y=(y0,y1,y2,y3) quads -> x=(x0,x1,y0,y1), y=(x2,x3,y2,y3)
static __device__ __forceinline__ void permswap32(u32 &x, u32 &y) {
    asm("v_permlane32_swap_b32 %0, %1" : "+v"(x), "+v"(y));
}
// -> x=(x0,y0,x2,y2), y=(x1,y1,x3,y3)
static __device__ __forceinline__ void permswap16(u32 &x, u32 &y) {
    asm("v_permlane16_swap_b32 %0, %1" : "+v"(x), "+v"(y));
}

// ---------------------------------------------------------------------------
// Fused prep: blocks [0,1024): mask bit-pack; [1024,2048): QKV convert;
// [2048,2560): W convert. All bodies are 256-thread; branch is block-uniform.
// ---------------------------------------------------------------------------
__global__ __launch_bounds__(256)
void prep_fused(const float* __restrict__ Qg, const float* __restrict__ Kg,
                const float* __restrict__ Vg, const int* __restrict__ Mg,
                const float* __restrict__ Wg,
                u16* __restrict__ Qb, u16* __restrict__ Kb, u16* __restrict__ Vt,
                u64* __restrict__ maskp, u16* __restrict__ Wb)
{
    const int bid = blockIdx.x;
    const int tid = threadIdx.x;
    __shared__ u16 Vl2[64][72];          // [d][k_row] (QKV branch only)

    if (bid < 1024) {
        // ---- mask bit-pack: maskp[row][t] = 64 bits for k = t*64.. ----
        const int wave = tid >> 6;
        const int lane = tid & 63;
        const int row  = bid * 4 + wave;              // 0 .. 4095
        const int* mp = Mg + (size_t)row * L_SEQ + lane;
        u64* op = maskp + (size_t)row * NT;
        for (int tt = 0; tt < NT; ++tt) {
            u64 b = __ballot(mp[tt * 64] != 0);
            if (lane == 0) op[tt] = b;
        }
    } else if (bid < 2048) {
        // ---- QKV prep: Qb = bf16(Q*0.125*log2e) [n,q,E]; Kb head-major
        //      [n,h,k,d]; Vt = V^T head-major [n,h,d,k]. ----
        const int b  = bid - 1024;
        const int tt = b & 31, hh = (b >> 5) & 15, nn = b >> 9;
        const int row = tid >> 2;            // 0..63
        const int dc  = (tid & 3) * 16;      // 0,16,32,48

        const size_t gin = ((size_t)(nn * L_SEQ) + tt * 64 + row) * EMB + hh * HDIM + dc;

        {
            const float qs = 0.125f * 1.44269504f;
            u16 o[16];
            cvt8(*(const float4*)(Qg + gin),     *(const float4*)(Qg + gin + 4),  o,     qs);
            cvt8(*(const float4*)(Qg + gin + 8), *(const float4*)(Qg + gin + 12), o + 8, qs);
            *(uint4*)(Qb + gin)     = *(const uint4*)o;
            *(uint4*)(Qb + gin + 8) = *(const uint4*)&o[8];
        }
        {
            u16 o[16];
            cvt8(*(const float4*)(Kg + gin),     *(const float4*)(Kg + gin + 4),  o,     1.f);
            cvt8(*(const float4*)(Kg + gin + 8), *(const float4*)(Kg + gin + 12), o + 8, 1.f);
            size_t ko = ((size_t)(nn * NHEAD + hh) * L_SEQ + tt * 64 + row) * HDIM + dc;
            *(uint4*)(Kb + ko)     = *(const uint4*)o;
            *(uint4*)(Kb + ko + 8) = *(const uint4*)&o[8];
        }
        {
            u16 o[16];
            cvt8(*(const float4*)(Vg + gin),     *(const float4*)(Vg + gin + 4),  o,     1.f);
            cvt8(*(const float4*)(Vg + gin + 8), *(const float4*)(Vg + gin + 12), o + 8, 1.f);
            #pragma unroll
            for (int j = 0; j < 16; ++j) Vl2[dc + j][row] = o[j];
        }
        __syncthreads();
        {
            const int d  = tid >> 2;
            const int kc = (tid & 3) * 16;
            size_t vo = ((size_t)(nn * NHEAD + hh) * HDIM + d) * L_SEQ + tt * 64 + kc;
            *(uint4*)(Vt + vo)     = *(const uint4*)&Vl2[d][kc];
            *(uint4*)(Vt + vo + 8) = *(const uint4*)&Vl2[d][kc + 8];
        }
    } else {
        // ---- W fp32 -> bf16 ----
        int i = ((bid - 2048) * 256 + tid) * 8;
        float4 a = *(const float4*)(Wg + i);
        float4 b4 = *(const float4*)(Wg + i + 4);
        u16 o[8];
        cvt8(a, b4, o, 1.f);
        *(uint4*)(Wb + i) = *(const uint4*)o;
    }
}

// ---------------------------------------------------------------------------
// PV step: O^T += V^T P^T for both q-sets; P arrives as Dw dwords (bf16x2
// k-pairs) and is redistributed to the B-fragment via permlane swaps.
// ---------------------------------------------------------------------------
static __device__ __forceinline__ void pv_step(
    const u32 (&Dwp)[2][8], const u16 (&Vb)[64][72],
    f32x4 (&acc)[2][4], int l16, int quad)
{
    #pragma unroll
    for (int kc = 0; kc < 2; ++kc) {
        bf16x8 pf[2];
        #pragma unroll
        for (int qs = 0; qs < 2; ++qs) {
            u32 b0 = Dwp[qs][4 * kc + 0], b2 = Dwp[qs][4 * kc + 2];
            permswap32(b0, b2); permswap16(b0, b2);
            u32 b1 = Dwp[qs][4 * kc + 1], b3 = Dwp[qs][4 * kc + 3];
            permswap32(b1, b3); permswap16(b1, b3);
            union { i32x4 i; bf16x8 v; } pu;
            pu.i[0] = (int)b0; pu.i[1] = (int)b1; pu.i[2] = (int)b2; pu.i[3] = (int)b3;
            pf[qs] = pu.v;
        }
        #pragma unroll
        for (int dc = 0; dc < 4; ++dc) {
            bf16x8 vf = *(const bf16x8*)&Vb[dc * 16 + l16][kc * 32 + quad * 8];
            acc[0][dc] = __builtin_amdgcn_mfma_f32_16x16x32_bf16(vf, pf[0], acc[0][dc], 0, 0, 0);
            acc[1][dc] = __builtin_amdgcn_mfma_f32_16x16x32_bf16(vf, pf[1], acc[1][dc], 0, 0, 0);
        }
    }
}

// ---------------------------------------------------------------------------
// One pipeline stage: stage tile t+1 into ring buffers, QK^T+softmax of tile
// t into Dwc, PV of tile t-1 from Dwp + V-ring, one barrier.
// Ring invariants (verified): K 2-ring (write (t+1)&1, read t&1), V 4-ring
// (write (t+1)&3, PV reads (t-1)&3) -- no same-iteration buffer overlap, and
// every cross-iteration reuse is separated by >=1 barrier.
// ---------------------------------------------------------------------------
static __device__ __forceinline__ void attn_tile(
    int t, int kbuf, int vprev, int kw, int vw,
    u32 (&Dwc)[2][8], u32 (&Dwp)[2][8],
    u16 (&Kl)[2][64][72], u16 (&Vl)[4][64][72],
    const bf16x8 (&qf)[2][2], f32x4 (&acc)[2][4], float (&ls)[2][4],
    uint4& kr0, uint4& kr1, uint4& vr0, uint4& vr1,
    u64& mr0, u64& mr1,
    const u16* kbase, const u16* vbase, const u64* mbase, int mqs,
    int srow, int scol, int l16, int quad)
{
    // ---- stage tile t+1 (regs -> LDS ring; nobody reads these buffers now) ----
    if (t < NT - 1) {
        *(uint4*)&Kl[kw][srow][scol]     = kr0;
        *(uint4*)&Kl[kw][srow][scol + 8] = kr1;
        *(uint4*)&Vl[vw][srow][scol]     = vr0;
        *(uint4*)&Vl[vw][srow][scol + 8] = vr1;
    }
    u64 mcur0 = mr0, mcur1 = mr1;
    if (t < NT - 1) { mr0 = mbase[t + 1]; mr1 = mbase[mqs + t + 1]; }
    // ---- prefetch tile t+2 global -> regs ----
    if (t < NT - 2) {
        const u16* kp = kbase + (size_t)((t + 2) * 64 + srow) * HDIM + scol;
        const u16* vp = vbase + (size_t)srow * L_SEQ + (t + 2) * 64 + scol;
        kr0 = *(const uint4*)kp;  kr1 = *(const uint4*)(kp + 8);
        vr0 = *(const uint4*)vp;  vr1 = *(const uint4*)(vp + 8);
    }

    // ---- S^T = K Q^T (both q-sets) + softmax -> Dwc ----
    const int sh = quad * 4;
    u32 mlo0 = (u32)mcur0 >> sh, mhi0 = (u32)(mcur0 >> 32) >> sh;
    u32 mlo1 = (u32)mcur1 >> sh, mhi1 = (u32)(mcur1 >> 32) >> sh;
    #pragma unroll
    for (int cc = 0; cc < 4; ++cc) {
        bf16x8 k0 = *(const bf16x8*)&Kl[kbuf][cc * 16 + l16][quad * 8];
        bf16x8 k1 = *(const bf16x8*)&Kl[kbuf][cc * 16 + l16][32 + quad * 8];
        f32x4 z0; z0[0]=0.f; z0[1]=0.f; z0[2]=0.f; z0[3]=0.f;
        f32x4 z1 = z0;
        z0 = __builtin_amdgcn_mfma_f32_16x16x32_bf16(k0, qf[0][0], z0, 0, 0, 0);
        z0 = __builtin_amdgcn_mfma_f32_16x16x32_bf16(k1, qf[0][1], z0, 0, 0, 0);
        z1 = __builtin_amdgcn_mfma_f32_16x16x32_bf16(k0, qf[1][0], z1, 0, 0, 0);
        z1 = __builtin_amdgcn_mfma_f32_16x16x32_bf16(k1, qf[1][1], z1, 0, 0, 0);

        #pragma unroll
        for (int qs = 0; qs < 2; ++qs) {
            const f32x4& z = (qs == 0) ? z0 : z1;
            u32 w = (cc < 2) ? ((qs == 0) ? mlo0 : mlo1)
                             : ((qs == 0) ? mhi0 : mhi1);
            float pv[4];
            #pragma unroll
            for (int r = 0; r < 4; ++r) {
                const int pos = (cc & 1) * 16 + r;
                int sm = (int)(w << (31 - pos)) >> 31;        // 0 or -1
                float p = __builtin_amdgcn_exp2f(z[r]);
                p = __int_as_float(__float_as_int(p) & sm);
                ls[qs][r] += p;
                pv[r] = p;
            }
            Dwc[qs][2 * cc]     = cvt_pk_bf16(pv[0], pv[1]);
            Dwc[qs][2 * cc + 1] = cvt_pk_bf16(pv[2], pv[3]);
        }
    }

    // ---- PV of tile t-1 (independent of this tile's softmax -> ILP) ----
    pv_step(Dwp, Vl[vprev], acc, l16, quad);

    __syncthreads();
}

// ---------------------------------------------------------------------------
// Flash attention, zero-bias exp2 softmax, swapped QK^T, in-register P
// redistribution. 128 q/block, 32 q/wave. Deferred-PV software pipeline:
// K 2-ring + V 4-ring LDS, one barrier per tile, softmax(t) overlaps PV(t-1).
// ---------------------------------------------------------------------------
__global__ __launch_bounds__(256, 2)
void attn_kernel(const u16* __restrict__ Qb, const u16* __restrict__ Kb,
                 const u16* __restrict__ Vt, const u64* __restrict__ maskp,
                 u16* __restrict__ Og)
{
    const int qblk = blockIdx.x;    // 0..15 (128 q-rows each)
    const int h    = blockIdx.y;
    const int n    = blockIdx.z;
    const int tid  = threadIdx.x;
    const int wave = tid >> 6;
    const int lane = tid & 63;
    const int l16  = lane & 15;
    const int quad = lane >> 4;

    __shared__ u16 Kl[2][64][72];   // K ring: [k][d]
    __shared__ u16 Vl[4][64][72];   // V ring: [d][k]

    const int q0 = qblk * 128 + wave * 32;

    bf16x8 qf[2][2];
    #pragma unroll
    for (int qs = 0; qs < 2; ++qs) {
        const u16* qp = Qb + ((size_t)(n * L_SEQ) + q0 + qs * 16 + l16) * EMB + h * HDIM;
        qf[qs][0] = *(const bf16x8*)(qp + quad * 8);
        qf[qs][1] = *(const bf16x8*)(qp + 32 + quad * 8);
    }

    f32x4 acc[2][4];
    #pragma unroll
    for (int qs = 0; qs < 2; ++qs)
        #pragma unroll
        for (int c = 0; c < 4; ++c)
            #pragma unroll
            for (int r = 0; r < 4; ++r) acc[qs][c][r] = 0.f;
    float ls[2][4];
    #pragma unroll
    for (int qs = 0; qs < 2; ++qs)
        #pragma unroll
        for (int r = 0; r < 4; ++r) ls[qs][r] = 0.f;

    u32 DwA[2][8], DwB[2][8];
    #pragma unroll
    for (int qs = 0; qs < 2; ++qs)
        #pragma unroll
        for (int i = 0; i < 8; ++i) { DwA[qs][i] = 0u; DwB[qs][i] = 0u; }

    const u16* kbase = Kb + (size_t)(n * NHEAD + h) * L_SEQ * HDIM;
    const u16* vbase = Vt + (size_t)(n * NHEAD + h) * HDIM * L_SEQ;
    const u64* mbase = maskp + ((size_t)(n * L_SEQ) + q0 + l16) * NT;
    const int  mqs   = 16 * NT;    // mask row stride for second q-set

    const int srow = tid >> 2;           // 0..63
    const int scol = (tid & 3) * 16;     // 0,16,32,48

    uint4 kr0, kr1, vr0, vr1;
    u64 mr0, mr1;

    // ---- prologue: tile0 regs -> K[0]/V[0]; zero V[3]; tile1 regs ----
    {
        const u16* kp = kbase + (size_t)srow * HDIM + scol;
        const u16* vp = vbase + (size_t)srow * L_SEQ + scol;
        kr0 = *(const uint4*)kp;  kr1 = *(const uint4*)(kp + 8);
        vr0 = *(const uint4*)vp;  vr1 = *(const uint4*)(vp + 8);
    }
    *(uint4*)&Kl[0][srow][scol]     = kr0;
    *(uint4*)&Kl[0][srow][scol + 8] = kr1;
    *(uint4*)&Vl[0][srow][scol]     = vr0;
    *(uint4*)&Vl[0][srow][scol + 8] = vr1;
    {
        u32* vz = (u32*)&Vl[3][0][0];
        #pragma unroll
        for (int i = 0; i < 9; ++i) vz[tid + i * 256] = 0u;   // 2304 u32 = 9216 B
    }
    {
        const u16* kp = kbase + (size_t)(64 + srow) * HDIM + scol;
        const u16* vp = vbase + (size_t)srow * L_SEQ + 64 + scol;
        kr0 = *(const uint4*)kp;  kr1 = *(const uint4*)(kp + 8);
        vr0 = *(const uint4*)vp;  vr1 = *(const uint4*)(vp + 8);
    }
    mr0 = mbase[0];
    mr1 = mbase[mqs];
    __syncthreads();

    // ---- main pipeline: 8 x 4 statically-indexed ring stages ----
    for (int j = 0; j < 8; ++j) {
        const int t = j * 4;
        attn_tile(t + 0, 0, 3, 1, 1, DwA, DwB, Kl, Vl, qf, acc, ls,
                  kr0, kr1, vr0, vr1, mr0, mr1, kbase, vbase, mbase, mqs,
                  srow, scol, l16, quad);
        attn_tile(t + 1, 1, 0, 0, 2, DwB, DwA, Kl, Vl, qf, acc, ls,
                  kr0, kr1, vr0, vr1, mr0, mr1, kbase, vbase, mbase, mqs,
                  srow, scol, l16, quad);
        attn_tile(t + 2, 0, 1, 1, 3, DwA, DwB, Kl, Vl, qf, acc, ls,
                  kr0, kr1, vr0, vr1, mr0, mr1, kbase, vbase, mbase, mqs,
                  srow, scol, l16, quad);
        attn_tile(t + 3, 1, 2, 0, 0, DwB, DwA, Kl, Vl, qf, acc, ls,
                  kr0, kr1, vr0, vr1, mr0, mr1, kbase, vbase, mbase, mqs,
                  srow, scol, l16, quad);
    }

    // ---- epilogue: PV of tile 31 (Dwc of u=3 is DwB; V ring slot 3) ----
    pv_step(DwB, Vl[3], acc, l16, quad);

    // ---- final: sum quads (same l16 = same q), normalize, write bf16 ----
    #pragma unroll
    for (int qs = 0; qs < 2; ++qs) {
        float s = (ls[qs][0] + ls[qs][1]) + (ls[qs][2] + ls[qs][3]);
        s += __shfl_xor(s, 16);
        s += __shfl_xor(s, 32);
        float inv = 1.f / s;

        u16* op = Og + ((size_t)(n * L_SEQ) + q0 + qs * 16 + l16) * EMB + h * HDIM + quad * 4;
        #pragma unroll
        for (int dc = 0; dc < 4; ++dc) {
            u32 u0 = cvt_pk_bf16(acc[qs][dc][0] * inv, acc[qs][dc][1] * inv);
            u32 u1 = cvt_pk_bf16(acc[qs][dc][2] * inv, acc[qs][dc][3] * inv);
            uint2 st; st.x = u0; st.y = u1;
            *(uint2*)(op + dc * 16) = st;
        }
    }
}

// ---------------------------------------------------------------------------
// out(fp32) = attn(4096x1024 bf16) @ Wb^T + bias.
// ---------------------------------------------------------------------------
__global__ __launch_bounds__(256, 4)
void out_gemm(const u16* __restrict__ A, const u16* __restrict__ B,
              const float* __restrict__ bias, float* __restrict__ out)
{
    const int bn  = blockIdx.x;   // 0..15
    const int bm  = blockIdx.y;   // 0..63
    const int tid = threadIdx.x;
    const int wave = tid >> 6;
    const int lane = tid & 63;
    const int l16  = lane & 15;
    const int quad = lane >> 4;
    const int wr = wave >> 1, wc = wave & 1;

    __shared__ u16 Al[64][72];
    __shared__ u16 Bl[64][72];

    f32x4 acc[2][2];
    #pragma unroll
    for (int i = 0; i < 2; ++i)
        #pragma unroll
        for (int j = 0; j < 2; ++j)
            #pragma unroll
            for (int r = 0; r < 4; ++r) acc[i][j][r] = 0.f;

    const int srow = tid >> 2;          // 0..63
    const int kc   = (tid & 3) * 16;    // 0,16,32,48

    const u16* ap = A + (size_t)(bm * 64 + srow) * EMB + kc;
    const u16* bp = B + (size_t)(bn * 64 + srow) * EMB + kc;

    uint4 ar0 = *(const uint4*)ap,        ar1 = *(const uint4*)(ap + 8);
    uint4 br0 = *(const uint4*)bp,        br1 = *(const uint4*)(bp + 8);

    for (int k0 = 0; k0 < EMB; k0 += 64) {
        __syncthreads();
        *(uint4*)&Al[srow][kc]     = ar0;
        *(uint4*)&Al[srow][kc + 8] = ar1;
        *(uint4*)&Bl[srow][kc]     = br0;
        *(uint4*)&Bl[srow][kc + 8] = br1;
        if (k0 + 64 < EMB) {
            ar0 = *(const uint4*)(ap + k0 + 64);  ar1 = *(const uint4*)(ap + k0 + 72);
            br0 = *(const uint4*)(bp + k0 + 64);  br1 = *(const uint4*)(bp + k0 + 72);
        }
        __syncthreads();

        #pragma unroll
        for (int kk = 0; kk < 2; ++kk) {
            bf16x8 af[2], bfr[2];
            #pragma unroll
            for (int i = 0; i < 2; ++i)
                af[i] = *(const bf16x8*)&Al[wr * 32 + i * 16 + l16][kk * 32 + quad * 8];
            #pragma unroll
            for (int j = 0; j < 2; ++j)
                bfr[j] = *(const bf16x8*)&Bl[wc * 32 + j * 16 + l16][kk * 32 + quad * 8];
            #pragma unroll
            for (int i = 0; i < 2; ++i)
                #pragma unroll
                for (int j = 0; j < 2; ++j)
                    acc[i][j] = __builtin_amdgcn_mfma_f32_16x16x32_bf16(af[i], bfr[j], acc[i][j], 0, 0, 0);
        }
    }

    #pragma unroll
    for (int j = 0; j < 2; ++j) {
        int col = bn * 64 + wc * 32 + j * 16 + l16;
        float bv = bias[col];
        #pragma unroll
        for (int i = 0; i < 2; ++i) {
            int row0 = bm * 64 + wr * 32 + i * 16 + quad * 4;
            #pragma unroll
            for (int r = 0; r < 4; ++r)
                out[(size_t)(row0 + r) * EMB + col] = acc[i][j][r] + bv;
        }
    }
}

extern "C" void kernel_launch(void* const* d_in, const int* in_sizes, int n_in,
                              void* d_out, int out_size, void* d_ws, size_t ws_size,
                              hipStream_t stream)
{
    const float* Vg = (const float*)d_in[0];
    const float* Kg = (const float*)d_in[1];
    const float* Qg = (const float*)d_in[2];
    const int*   Mg = (const int*)d_in[3];
    const float* Wg = (const float*)d_in[4];
    const float* Bg = (const float*)d_in[5];
    float* Og = (float*)d_out;

    const size_t QKV = (size_t)NBATCH * L_SEQ * EMB;   // 4M elems
    char* ws = (char*)d_ws;
    u16* attn_ws = (u16*)ws;                         // 8 MB
    u16* Wb      = (u16*)(ws + QKV * 2);             // 2 MB
    u16* Qb      = (u16*)(ws + QKV * 2 + 2 * 1024 * 1024);
    u16* Kb      = Qb + QKV;                         // 8 MB each
    u16* Vt      = Kb + QKV;
    u64* maskp   = (u64*)(Vt + QKV);                 // 1 MB

    prep_fused<<<dim3(2560), 256, 0, stream>>>(Qg, Kg, Vg, Mg, Wg,
                                               Qb, Kb, Vt, maskp, Wb);

    dim3 g1(L_SEQ / 128, NHEAD, NBATCH);
    attn_kernel<<<g1, 256, 0, stream>>>(Qb, Kb, Vt, maskp, attn_ws);

    dim3 g2(EMB / 64, (NBATCH * L_SEQ) / 64);
    out_gemm<<<g2, 256, 0, stream>>>(attn_ws, Wb, Bg, Og);
}